// Round 1
// baseline (4612.980 us; speedup 1.0000x reference)
//
#include <hip/hip_runtime.h>
#include <hip/hip_bf16.h>
#include <cstdio>

// SHRED: 2-layer LSTM (B=64,T=512,I=64,H=512) + MLP decoder 512->1024->2048->16384.
//
// Round 1 design: pipeline-skewed per-step kernels (513 graph launches).
//   launch k: layer0 computes h0[k] (k<512); layer1 computes h1[k-1] (k>=1).
//   Kernel boundaries provide the cross-workgroup ordering; no in-kernel sync.
// Compute: mfma_f32_16x16x32_bf16, fp32 accum, fp32 cell state, bf16 h.
// A-tile row order j_local = u_local*4 + gate  =>  with D mapping
// row=(lane>>4)*4+reg, col=lane&15, each lane's 4 regs are i,f,g,o of one
// (unit,batch) pair -> pointwise LSTM update is lane-local.
// Weights pre-packed once into fragment order; biases pre-summed; x -> bf16.

#define B_  64
#define T_  512
#define I_  64
#define H_  512
#define D1_ 1024
#define D2_ 2048
#define O_  16384

typedef __attribute__((ext_vector_type(8))) short bf16x8_t;
typedef __attribute__((ext_vector_type(4))) float f32x4_t;
typedef unsigned short ushort_t;

__device__ inline ushort_t f2bf(float f) {
    return __builtin_bit_cast(ushort_t, __float2bfloat16(f));
}
__device__ inline float sigm(float x) { return 1.0f / (1.0f + __expf(-x)); }
__device__ inline float tanhf_(float x) {
    float cx = fminf(fmaxf(x, -15.f), 15.f);
    float e = __expf(2.f * cx);
    return (e - 1.f) / (e + 1.f);
}

// ---- prep kernels (run once per call, cheap) -------------------------------

// packL0: [128 utiles][18 ksteps][64 lanes][8] bf16.
// A-frag: lane l holds rows j_local=l&15, k = kk*32 + 8*(l>>4) + i.
// j_local = u_local*4 + gate; weight row = gate*H + u.
// K-concat for layer0: [h0_prev (512) ; x_t (64)] -> Whh0 then Wih0.
__global__ void pack_l0(const float* __restrict__ Wih0, const float* __restrict__ Whh0,
                        ushort_t* __restrict__ pack) {
    int idx = blockIdx.x * 256 + threadIdx.x;       // < 128*18*64
    int l  = idx & 63;
    int kk = (idx >> 6) % 18;
    int tu = idx / (18 * 64);
    int jl = l & 15, g8 = (l >> 4) * 8;
    int gate = jl & 3, u = tu * 4 + (jl >> 2);
    int wrow = gate * H_ + u;
    int kg = kk * 32 + g8;                          // chunk of 8 never straddles 512
    const float* s = (kg < H_) ? (Whh0 + (size_t)wrow * H_ + kg)
                               : (Wih0 + (size_t)wrow * I_ + (kg - H_));
    ushort_t* d = pack + (size_t)idx * 8;
#pragma unroll
    for (int i = 0; i < 8; i++) d[i] = f2bf(s[i]);
}

// packL1: [128][32][64][8]. K-concat: [h0_t (512); h1_prev (512)] -> Wih1 then Whh1.
__global__ void pack_l1(const float* __restrict__ Wih1, const float* __restrict__ Whh1,
                        ushort_t* __restrict__ pack) {
    int idx = blockIdx.x * 256 + threadIdx.x;       // < 128*32*64
    int l  = idx & 63;
    int kk = (idx >> 6) & 31;
    int tu = idx >> 11;
    int jl = l & 15, g8 = (l >> 4) * 8;
    int gate = jl & 3, u = tu * 4 + (jl >> 2);
    int wrow = gate * H_ + u;
    int kg = kk * 32 + g8;
    const float* s = (kg < H_) ? (Wih1 + (size_t)wrow * H_ + kg)
                               : (Whh1 + (size_t)wrow * H_ + (kg - H_));
    ushort_t* d = pack + (size_t)idx * 8;
#pragma unroll
    for (int i = 0; i < 8; i++) d[i] = f2bf(s[i]);
}

// bsum[layer][u][gate] = bih[gate*H+u] + bhh[gate*H+u]
__global__ void pack_bias(const float* __restrict__ bih0, const float* __restrict__ bhh0,
                          const float* __restrict__ bih1, const float* __restrict__ bhh1,
                          float* __restrict__ bsum) {
    int idx = blockIdx.x * 256 + threadIdx.x;       // < 4096
    int layer = idx >> 11;
    int rest = idx & 2047;
    int u = rest >> 2, gate = rest & 3;
    const float* a = layer ? bih1 : bih0;
    const float* b = layer ? bhh1 : bhh0;
    bsum[idx] = a[gate * H_ + u] + b[gate * H_ + u];
}

// x[B][T][I] fp32 -> xbf[T][B][I] bf16
__global__ void conv_x(const float* __restrict__ x, ushort_t* __restrict__ xbf) {
    int idx = blockIdx.x * 256 + threadIdx.x;       // < 64*512*64
    int c = idx & 63;
    int t = (idx >> 6) & 511;
    int b = idx >> 15;
    xbf[(size_t)t * 4096 + b * 64 + c] = f2bf(x[idx]);
}

// ---- recurrent step --------------------------------------------------------
// grid = 256 WGs x 256 thr. WG w<128: layer0 utile w; else layer1 utile w-128.
// wave v = b-block. Per wave: one 16x16 D tile (16 gate-cols x 16 batch).
__global__ __launch_bounds__(256) void lstm_step(
    int k,
    const ushort_t* __restrict__ packL0, const ushort_t* __restrict__ packL1,
    const float* __restrict__ bsum, const ushort_t* __restrict__ xbf,
    ushort_t* __restrict__ hbuf0, ushort_t* __restrict__ hbuf1,
    float* __restrict__ c0, float* __restrict__ c1)
{
    __shared__ uint4 aLDS4[2048];                   // 32 KiB, holds A-frags
    int w = blockIdx.x, tid = threadIdx.x;
    int l = tid & 63, v = tid >> 6;
    int layer = (w >= 128);
    int tu = layer ? (w - 128) : w;
    if (!layer && k >= T_) return;                  // WG-uniform
    if (layer && k == 0) return;

    int nk = layer ? 32 : 18;
    const ushort_t* src = layer ? (packL1 + (size_t)tu * (32 * 512))
                                : (packL0 + (size_t)tu * (18 * 512));
    {
        const uint4* s4 = (const uint4*)src;
        for (int i = tid; i < nk * 64; i += 256) aLDS4[i] = s4[i];
    }
    __syncthreads();

    int u_loc = l >> 4;
    int bb = v * 16 + (l & 15);
    int u = tu * 4 + u_loc;
    const float* bp = bsum + layer * 2048 + u * 4;
    f32x4_t acc;
    acc[0] = bp[0]; acc[1] = bp[1]; acc[2] = bp[2]; acc[3] = bp[3];

    const int HS = 64 * 512;
    // both layers read h0 slot (k-1)&1 == (k+1)&1
    const ushort_t* h0r = hbuf0 + ((k + 1) & 1) * HS + bb * 512;
    // layer0 tail K-source: x_t row; layer1 tail: h1[k-2] slot k&1
    const ushort_t* srcHi = layer ? (hbuf1 + (k & 1) * HS + bb * 512)
                                  : (xbf + (size_t)k * 4096 + bb * 64);
    int g8 = (l >> 4) * 8;

    const bf16x8_t* aF = (const bf16x8_t*)aLDS4;
    for (int kk = 0; kk < nk; ++kk) {
        bf16x8_t a = aF[kk * 64 + l];
        const ushort_t* bp_ = (kk < 16) ? (h0r + kk * 32 + g8)
                                        : (srcHi + (kk - 16) * 32 + g8);
        bf16x8_t b = *(const bf16x8_t*)bp_;
        acc = __builtin_amdgcn_mfma_f32_16x16x32_bf16(a, b, acc, 0, 0, 0);
    }

    // lane-local LSTM pointwise update: regs = i,f,g,o of (u, bb)
    float xi = sigm(acc[0]);
    float xf = sigm(acc[1]);
    float xg = tanhf_(acc[2]);
    float xo = sigm(acc[3]);
    float* cb = layer ? c1 : c0;
    size_t ci = (size_t)u * 64 + bb;
    float cn = xf * cb[ci] + xi * xg;
    cb[ci] = cn;
    float hn = xo * tanhf_(cn);
    // layer0 writes h0[k] slot k&1; layer1 writes h1[k-1] slot (k+1)&1
    ushort_t* hw = layer ? (hbuf1 + ((k + 1) & 1) * HS) : (hbuf0 + (k & 1) * HS);
    hw[(size_t)bb * 512 + u] = f2bf(hn);
}

// ---- decoder GEMM: out[64][ncols] = act[64][K] @ W[ncols][K]^T + bias ------
// W fp32 converted inline to bf16 fragments (memory-bound anyway for W3).
template <int NK, bool RELU, bool OUTBF>
__global__ __launch_bounds__(256) void dec_gemm(
    const float* __restrict__ W, const float* __restrict__ bias,
    const ushort_t* __restrict__ act, void* __restrict__ outp, int ncols)
{
    int tile = blockIdx.x, tid = threadIdx.x;
    int l = tid & 63, v = tid >> 6;
    int bb = v * 16 + (l & 15);
    int jA = tile * 16 + (l & 15);
    int g8 = (l >> 4) * 8;
    const float* wrow = W + (size_t)jA * (NK * 32);
    const ushort_t* arow = act + (size_t)bb * (NK * 32);
    f32x4_t acc = {0.f, 0.f, 0.f, 0.f};
    for (int kk = 0; kk < NK; ++kk) {
        int kg = kk * 32 + g8;
        float4 w0 = *(const float4*)(wrow + kg);
        float4 w1 = *(const float4*)(wrow + kg + 4);
        bf16x8_t af;
        af[0] = (short)f2bf(w0.x); af[1] = (short)f2bf(w0.y);
        af[2] = (short)f2bf(w0.z); af[3] = (short)f2bf(w0.w);
        af[4] = (short)f2bf(w1.x); af[5] = (short)f2bf(w1.y);
        af[6] = (short)f2bf(w1.z); af[7] = (short)f2bf(w1.w);
        bf16x8_t bf = *(const bf16x8_t*)(arow + kg);
        acc = __builtin_amdgcn_mfma_f32_16x16x32_bf16(af, bf, acc, 0, 0, 0);
    }
    int j0 = tile * 16 + (l >> 4) * 4;
    float r[4];
#pragma unroll
    for (int i = 0; i < 4; i++) {
        r[i] = acc[i] + bias[j0 + i];
        if (RELU) r[i] = fmaxf(r[i], 0.f);
    }
    if (OUTBF) {
        ushort_t* o = (ushort_t*)outp + (size_t)bb * ncols + j0;
        unsigned int lo = (unsigned)f2bf(r[0]) | ((unsigned)f2bf(r[1]) << 16);
        unsigned int hi = (unsigned)f2bf(r[2]) | ((unsigned)f2bf(r[3]) << 16);
        uint2 q; q.x = lo; q.y = hi;
        *(uint2*)o = q;
    } else {
        float* o = (float*)outp + (size_t)bb * ncols + j0;
        float4 t4; t4.x = r[0]; t4.y = r[1]; t4.z = r[2]; t4.w = r[3];
        *(float4*)o = t4;
    }
}

// ---- host ------------------------------------------------------------------
extern "C" void kernel_launch(void* const* d_in, const int* in_sizes, int n_in,
                              void* d_out, int out_size, void* d_ws, size_t ws_size,
                              hipStream_t stream)
{
    const float* x    = (const float*)d_in[0];
    const float* Wih0 = (const float*)d_in[1];
    const float* Whh0 = (const float*)d_in[2];
    const float* bih0 = (const float*)d_in[3];
    const float* bhh0 = (const float*)d_in[4];
    const float* Wih1 = (const float*)d_in[5];
    const float* Whh1 = (const float*)d_in[6];
    const float* bih1 = (const float*)d_in[7];
    const float* bhh1 = (const float*)d_in[8];
    const float* W1   = (const float*)d_in[9];
    const float* b1   = (const float*)d_in[10];
    const float* W2   = (const float*)d_in[11];
    const float* b2   = (const float*)d_in[12];
    const float* W3   = (const float*)d_in[13];
    const float* b3   = (const float*)d_in[14];

    char* ws = (char*)d_ws;
    size_t off = 0;
    auto take = [&](size_t bytes) -> char* {
        char* p = ws + off;
        off = (off + bytes + 255) & ~(size_t)255;
        return p;
    };
    ushort_t* packL0 = (ushort_t*)take((size_t)128 * 18 * 64 * 8 * 2);  // 2.25 MiB
    ushort_t* packL1 = (ushort_t*)take((size_t)128 * 32 * 64 * 8 * 2);  // 4 MiB
    float*    bsum   = (float*)take(2 * 2048 * 4);
    ushort_t* xbf    = (ushort_t*)take((size_t)512 * 64 * 64 * 2);      // 4 MiB
    char* zbase = ws + off;
    ushort_t* hbuf0  = (ushort_t*)take(2 * 64 * 512 * 2);
    ushort_t* hbuf1  = (ushort_t*)take(2 * 64 * 512 * 2);
    float*    c0     = (float*)take(512 * 64 * 4);
    float*    c1     = (float*)take(512 * 64 * 4);
    size_t zbytes = (size_t)((ws + off) - zbase);
    ushort_t* y1 = (ushort_t*)take(64 * 1024 * 2);
    ushort_t* y2 = (ushort_t*)take(64 * 2048 * 2);
    if (off > ws_size) {
        fprintf(stderr, "kernel_launch: ws too small: need %zu have %zu\n", off, ws_size);
        return;
    }

    // prep (every call; deterministic)
    pack_l0<<<(128 * 18 * 64) / 256, 256, 0, stream>>>(Wih0, Whh0, packL0);
    pack_l1<<<(128 * 32 * 64) / 256, 256, 0, stream>>>(Wih1, Whh1, packL1);
    pack_bias<<<16, 256, 0, stream>>>(bih0, bhh0, bih1, bhh1, bsum);
    conv_x<<<(64 * 512 * 64) / 256, 256, 0, stream>>>(x, xbf);
    hipMemsetAsync(zbase, 0, zbytes, stream);   // zero h rings + cell state

    // recurrent pipeline: 513 launches, layer0 step k + layer1 step k-1
    for (int k = 0; k <= T_; ++k)
        lstm_step<<<256, 256, 0, stream>>>(k, packL0, packL1, bsum, xbf,
                                           hbuf0, hbuf1, c0, c1);

    // final top hidden state h1[511] lives in slot (511)&1 == 1
    const ushort_t* h1f = hbuf1 + 1 * (64 * 512);
    dec_gemm<16, true,  true ><<<  64, 256, 0, stream>>>(W1, b1, h1f, y1, D1_);
    dec_gemm<32, true,  true ><<< 128, 256, 0, stream>>>(W2, b2, y1, y2, D2_);
    dec_gemm<64, false, false><<<1024, 256, 0, stream>>>(W3, b3, y2, d_out, O_);
}